// Round 16
// baseline (85.784 us; speedup 1.0000x reference)
//
#include <hip/hip_runtime.h>

// ---------------------------------------------------------------------------
// PANet disparity head — TWO-kernel pipeline for MI355X (gfx950).
//
// K1 panet_encode (R9-proven): encoder (x,y -> bf16 xf,yf in ws) + wd packed
//   as 400B-stride LDS image + bd*log2e.
// K2 panet_corr (R16): the VGPR rule, finally: allocator budgets by WG SIZE
//   alone — 512thr->128 cap (R1/2/13/14/15), 1024thr->64 (R4/5),
//   256thr->224 GRANTED CLEAN (R12). So: 256-thr blocks, and SPEND the regs:
//   * 2x4 mfma32 blocking per wave (64 rows x 128 cols): acc 128 regs,
//     live ~190 < 224. DS reads/MFMA 1.0 -> 0.75; total waves HALVED.
//   * full wd (76.8KB) + 8-copy hankel + bd in 89KB static LDS; 1 block/CU;
//     ONE barrier; waves free-run (1 wave/SIMD: ILP from 8 indep acc chains).
//   * no-max softmax (R12/13/15-validated), inline bd, raw v_exp_f32.
//   Per-CU pipes: DS ~19us, MFMA 15.5 (floor), VALU ~2.8/wave -> K2 ~30-42us.
// ---------------------------------------------------------------------------

typedef __attribute__((ext_vector_type(8)))  __bf16 bf16x8;
typedef __attribute__((ext_vector_type(4)))  float  f32x4;
typedef __attribute__((ext_vector_type(16))) float  f32x16;

#define MFMA32(a,b,c) __builtin_amdgcn_mfma_f32_32x32x16_bf16((a),(b),(c),0,0,0)
#define MFMA16(a,b,c) __builtin_amdgcn_mfma_f32_16x16x32_bf16((a),(b),(c),0,0,0)

constexpr int WW  = 512;
constexpr int HW  = 256 * 512;      // 131072
constexpr int CHW = 32 * HW;        // 4194304
constexpr float LOG2E = 1.4426950408889634f;

// d_ws layout (R9):
constexpr size_t XFB_OFF = 0;                   // bf16 [2 img][512 row][512 w]
constexpr int    STB     = 25600;               // 64 rows x 400 B
constexpr size_t WDP_OFF = 2 * 262144 * 2;      // 1048576: wd image 3*25600
constexpr size_t BDP_OFF = WDP_OFF + 3 * STB;   // f32[192] = bd * LOG2E

// ---------------------------------------------------------------- K1
__global__ __launch_bounds__(512)
void panet_encode(const float* __restrict__ gx,  const float* __restrict__ gy,
                  const float* __restrict__ gw1, const float* __restrict__ gb1,
                  const float* __restrict__ gw2, const float* __restrict__ gb2,
                  const float* __restrict__ gw3, const float* __restrict__ gb3,
                  const float* __restrict__ gwd, const float* __restrict__ gbd,
                  char* __restrict__ ws)
{
  const int blk = blockIdx.x;
  const int tid = threadIdx.x;

  if (blk >= 1024) {                          // ---- packer blocks 1024..1039
    const int pi = blk - 1024;                // 16 blocks, 12 o-rows each
    unsigned short* wdp = (unsigned short*)(ws + WDP_OFF);
    for (int idx = tid; idx < 12 * 200; idx += 512) {  // 200 ushort per 400B row
      const int oo = idx / 200;
      const int k  = idx - oo * 200;
      const int o  = 12 * pi + oo;
      unsigned short v = 0;
      if (k < 192) v = __builtin_bit_cast(unsigned short, (__bf16)gwd[o * 192 + k]);
      wdp[(o >> 6) * 12800 + (o & 63) * 200 + k] = v;
    }
    if (pi == 0) {
      float* bdp = (float*)(ws + BDP_OFF);
      if (tid < 192) bdp[tid] = gbd[tid] * LOG2E;
    }
    return;
  }

  // ---- encoder: blk -> (t = image, bh). Proven R3..R15 body.
  const int t    = blk >> 9;
  const int bh   = blk & 511;
  const int lane = tid & 63;
  const int m    = lane & 15;
  const int g    = lane >> 4;
  const int wid  = tid >> 6;

  bf16x8 A1[4], A2[2][2];
  f32x4  bias1[4], bias2[2], w3v[2];
  #pragma unroll
  for (int Mt = 0; Mt < 4; ++Mt) {
    const float* p = gw1 + (16 * Mt + m) * 32 + 4 * g;
    const f32x4 u0 = *(const f32x4*)p;
    const f32x4 u1 = *(const f32x4*)(p + 16);
    #pragma unroll
    for (int j = 0; j < 4; ++j) { A1[Mt][j] = (__bf16)u0[j]; A1[Mt][j + 4] = (__bf16)u1[j]; }
    bias1[Mt] = *(const f32x4*)(gb1 + 16 * Mt + 4 * g);
  }
  #pragma unroll
  for (int Mt = 0; Mt < 2; ++Mt) {
    #pragma unroll
    for (int s = 0; s < 2; ++s) {
      const float* p = gw2 + (16 * Mt + m) * 64 + 32 * s + 4 * g;
      const f32x4 u0 = *(const f32x4*)p;
      const f32x4 u1 = *(const f32x4*)(p + 16);
      #pragma unroll
      for (int j = 0; j < 4; ++j) { A2[Mt][s][j] = (__bf16)u0[j]; A2[Mt][s][j + 4] = (__bf16)u1[j]; }
    }
    bias2[Mt] = *(const f32x4*)(gb2 + 16 * Mt + 4 * g);
    w3v[Mt]   = *(const f32x4*)(gw3 + 16 * Mt + 4 * g);
  }
  const float b3s = gb3[0];
  const f32x4 zf4 = {0.f, 0.f, 0.f, 0.f};
  const float* base = (t ? gy : gx) + (bh >> 8) * CHW + (bh & 255) * WW;
  unsigned short* xfb = (unsigned short*)(ws + XFB_OFF) + t * 262144 + bh * 512;

  for (int u = wid; u < 32; u += 8) {
    const int w0 = u << 4;
    const float* src = base + w0 + m;

    bf16x8 B1;
    #pragma unroll
    for (int j = 0; j < 8; ++j) {
      const int c = 16 * (j >> 2) + 4 * g + (j & 3);
      B1[j] = (__bf16)fmaxf(src[c * HW], 0.f);
    }
    f32x4 acc1[4];
    #pragma unroll
    for (int Mt = 0; Mt < 4; ++Mt) acc1[Mt] = MFMA16(A1[Mt], B1, zf4);

    bf16x8 B2[2];
    #pragma unroll
    for (int s = 0; s < 2; ++s) {
      #pragma unroll
      for (int j = 0; j < 4; ++j) {
        B2[s][j]     = (__bf16)fmaxf(acc1[2 * s][j]     + bias1[2 * s][j],     0.f);
        B2[s][j + 4] = (__bf16)fmaxf(acc1[2 * s + 1][j] + bias1[2 * s + 1][j], 0.f);
      }
    }
    f32x4 acc2[2];
    #pragma unroll
    for (int Mt = 0; Mt < 2; ++Mt)
      acc2[Mt] = MFMA16(A2[Mt][1], B2[1], MFMA16(A2[Mt][0], B2[0], zf4));

    float s3 = 0.f;
    #pragma unroll
    for (int Mt = 0; Mt < 2; ++Mt)
      #pragma unroll
      for (int r = 0; r < 4; ++r)
        s3 += w3v[Mt][r] * fmaxf(acc2[Mt][r] + bias2[Mt][r], 0.f);
    s3 += __shfl_xor(s3, 16);
    s3 += __shfl_xor(s3, 32);
    const float val = fmaxf(s3 + b3s, 0.f);

    if (lane < 16)
      xfb[w0 + m] = __builtin_bit_cast(unsigned short, (__bf16)val);
  }
}

// ---------------------------------------------------------------- K2
constexpr int CPS    = 1424;                  // hankel copy stride (bytes)
constexpr int K2_HK  = 76800;                 // after full wd image
constexpr int K2_BD  = K2_HK + 8 * CPS;       // 88192: f32[192]
constexpr int K2_LDS = K2_BD + 768;           // 88960 B STATIC

__global__ __launch_bounds__(256)
void panet_corr(const char* __restrict__ ws, float* __restrict__ gout)
{
  __shared__ __align__(16) char lds[K2_LDS];
  const int blk  = blockIdx.x;                // dir*512 + bh
  const int dir  = blk >> 9;
  const int bh   = blk & 511;
  const int tid  = threadIdx.x;
  const int lane = tid & 63;
  const int l31  = lane & 31;
  const int h    = lane >> 5;                 // lane half
  const int wid  = tid >> 6;                  // 4 waves, 128 cols each

  const unsigned short* xfbu = (const unsigned short*)(ws + XFB_OFF);
  const unsigned short* hs = xfbu + (dir ? 262144 : 0) + bh * 512;  // hankel src
  const unsigned short* ss = xfbu + (dir ? 0 : 262144) + bh * 512;  // scale src

  // ---- stage wd image + bd; build 8-copy hankel (zeros beyond 511)
  {
    const f32x4* src = (const f32x4*)(ws + WDP_OFF);
    f32x4* dst = (f32x4*)lds;
    #pragma unroll 4
    for (int i = tid; i < 4800; i += 256) dst[i] = src[i];
    if (tid < 192)
      ((float*)(lds + K2_BD))[tid] = ((const float*)(ws + BDP_OFF))[tid];
  }
  for (int e = tid; e < 712; e += 256) {
    #pragma unroll
    for (int c = 0; c < 8; ++c) {
      const int j = e + c;
      unsigned short v = 0;
      if (j <= 511) v = hs[dir ? (511 - j) : j];
      ((unsigned short*)(lds + K2_HK + c * CPS))[e] = v;
    }
  }
  __syncthreads();                             // the ONLY barrier

  // per-lane B bases + scales: 4 col-tiles of 32 (128 cols per wave)
  int boff[4]; float sc[4];
  #pragma unroll
  for (int ct = 0; ct < 4; ++ct) {
    const int col = wid * 128 + ct * 32 + l31;
    const int I0  = dir ? (511 - col) : col;
    const int cc  = I0 & 7;
    boff[ct] = K2_HK + cc * CPS + 2 * (I0 - cc) + 16 * h;
    sc[ct]  = LOG2E * __builtin_bit_cast(float, (unsigned)ss[col] << 16);
  }

  float stS[4] = {0.f, 0.f, 0.f, 0.f};
  float stW[4] = {0.f, 0.f, 0.f, 0.f};

  for (int s = 0; s < 3; ++s) {               // 3 x 64 wd rows
    const char* abase = lds + (64 * s + l31) * 400 + 16 * h;
    f32x16 a0[4] = {{0}, {0}, {0}, {0}};      // rt=0 rows, 4 col-tiles
    f32x16 a1[4] = {{0}, {0}, {0}, {0}};      // rt=1 rows (+32)
    #pragma unroll 2
    for (int ks = 0; ks < 12; ++ks) {         // K = 12*16 = 192
      const bf16x8 af0 = *(const bf16x8*)(abase + 32 * ks);
      const bf16x8 af1 = *(const bf16x8*)(abase + 12800 + 32 * ks);
      bf16x8 bf[4];
      #pragma unroll
      for (int ct = 0; ct < 4; ++ct)
        bf[ct] = *(const bf16x8*)(lds + boff[ct] + 32 * ks);
      #pragma unroll
      for (int ct = 0; ct < 4; ++ct) {
        a0[ct] = MFMA32(af0, bf[ct], a0[ct]);
        a1[ct] = MFMA32(af1, bf[ct], a1[ct]);
      }
    }

    // NO-max softmax accumulation (exp2 domain; logits bounded), inline bd
    const float obase = (float)(64 * s + 4 * h);
    #pragma unroll
    for (int ct = 0; ct < 4; ++ct) {
      float ls0 = 0.f, ls1 = 0.f, lw0 = 0.f, lw1 = 0.f;
      #pragma unroll
      for (int q = 0; q < 4; ++q) {
        const f32x4 bd0 = *(const f32x4*)(lds + K2_BD + (64 * s + 8 * q + 4 * h) * 4);
        const f32x4 bd1 = *(const f32x4*)(lds + K2_BD + (64 * s + 8 * q + 4 * h + 32) * 4);
        #pragma unroll
        for (int r = 0; r < 4; ++r) {
          const int i = 4 * q + r;
          const float L0 = fmaf(sc[ct], a0[ct][i], bd0[r]);
          const float L1 = fmaf(sc[ct], a1[ct][i], bd1[r]);
          const float p0 = __builtin_amdgcn_exp2f(L0);
          const float p1 = __builtin_amdgcn_exp2f(L1);
          const float c  = (float)(r + 8 * q);          // o - obase (rt=0)
          ls0 += p0;  ls1 += p1;
          lw0 = fmaf(c, p0, lw0);
          lw1 = fmaf(c + 32.f, p1, lw1);
        }
      }
      const float ls = ls0 + ls1;
      const float lw = fmaf(obase, ls, lw0 + lw1);
      stS[ct] += ls;
      stW[ct] += lw;
    }
  }

  // combine the two lane-halves (o split by h) and write
  float* outp = gout + dir * 262144 + bh * 512;
  #pragma unroll
  for (int ct = 0; ct < 4; ++ct) {
    float sr = stS[ct];
    float wr = stW[ct];
    sr += __shfl_xor(sr, 32);
    wr += __shfl_xor(wr, 32);
    if (lane < 32) outp[wid * 128 + ct * 32 + l31] = wr / sr;
  }
}

extern "C" void kernel_launch(void* const* d_in, const int* in_sizes, int n_in,
                              void* d_out, int out_size, void* d_ws, size_t ws_size,
                              hipStream_t stream) {
  const float* x  = (const float*)d_in[0];
  const float* y  = (const float*)d_in[1];
  const float* w1 = (const float*)d_in[2];
  const float* b1 = (const float*)d_in[3];
  const float* w2 = (const float*)d_in[4];
  const float* b2 = (const float*)d_in[5];
  const float* w3 = (const float*)d_in[6];
  const float* b3 = (const float*)d_in[7];
  const float* wd = (const float*)d_in[8];
  const float* bd = (const float*)d_in[9];
  char* ws = (char*)d_ws;

  panet_encode<<<1040, 512, 0, stream>>>(x, y, w1, b1, w2, b2, w3, b3, wd, bd, ws);
  panet_corr<<<1024, 256, 0, stream>>>(ws, (float*)d_out);
}